// Round 4
// baseline (1015.221 us; speedup 1.0000x reference)
//
#include <hip/hip_runtime.h>
#include <math.h>

#define BLOCK 256
#define DPB   64      // directions per block = one wave's lanes
#define NSUB  4       // vertex sub-chunks, one per wave
#define VMAX  1024    // max verts stageable in LDS fast path
#define LBv 1e-20f
#define UBv 1e20f

typedef float f32x2 __attribute__((ext_vector_type(2)));

// Raw HW transcendentals: v_log_f32 / v_exp_f32 (~1 ulp).
// Edge semantics used deliberately: log2(0) = -inf, exp2(-inf) = 0 (c1>0).
#if __has_builtin(__builtin_amdgcn_logf) && __has_builtin(__builtin_amdgcn_exp2f)
__device__ __forceinline__ float fast_log2(float x) { return __builtin_amdgcn_logf(x); }
__device__ __forceinline__ float fast_exp2(float x) { return __builtin_amdgcn_exp2f(x); }
#else
__device__ __forceinline__ float fast_log2(float x) { return log2f(x); }
__device__ __forceinline__ float fast_exp2(float x) { return exp2f(x); }
#endif

// FORCED packed fp32 math (gfx90a+ VOP3P). Non-volatile asm: scheduler may
// interleave, CSE is blocked only per-instance. "v" on a 64-bit ext_vector
// allocates an aligned VGPR pair.
__device__ __forceinline__ f32x2 apk_mul(f32x2 a, f32x2 b) {
    f32x2 d;
    asm("v_pk_mul_f32 %0, %1, %2" : "=v"(d) : "v"(a), "v"(b));
    return d;
}
__device__ __forceinline__ f32x2 apk_fma(f32x2 a, f32x2 b, f32x2 c) {
    f32x2 d;
    asm("v_pk_fma_f32 %0, %1, %2, %3" : "=v"(d) : "v"(a), "v"(b), "v"(c));
    return d;
}

// ---------------- Kernel 1: once-per-tile work ----------------
__global__ __launch_bounds__(BLOCK) void mcnet_mean(
    const float* __restrict__ verts, const float* __restrict__ dirs,
    float* __restrict__ out,
    int NT, int V, int D,
    size_t offMV, size_t offDIR, size_t offLV, size_t offZ)
{
    __shared__ float red[12];
    const int tid  = threadIdx.x;
    const int lane = tid & 63;
    const int wid  = tid >> 6;
    const int tile = blockIdx.x;

    const float* vp0 = verts + (size_t)tile * V * 3;

    float sx = 0.f, sy = 0.f, sz = 0.f;
    for (int v = tid; v < V; v += BLOCK) {
        sx += vp0[3 * v + 0]; sy += vp0[3 * v + 1]; sz += vp0[3 * v + 2];
    }
    #pragma unroll
    for (int off = 32; off > 0; off >>= 1) {
        sx += __shfl_xor(sx, off);
        sy += __shfl_xor(sy, off);
        sz += __shfl_xor(sz, off);
    }
    if (lane == 0) { red[wid * 3 + 0] = sx; red[wid * 3 + 1] = sy; red[wid * 3 + 2] = sz; }
    __syncthreads();
    const float inv = 1.0f / (float)V;
    const float mx = (red[0] + red[3] + red[6] + red[9])  * inv;
    const float my = (red[1] + red[4] + red[7] + red[10]) * inv;
    const float mz = (red[2] + red[5] + red[8] + red[11]) * inv;

    for (int v = tid; v < V; v += BLOCK) {
        size_t o = offLV + ((size_t)tile * V + v) * 3;
        out[o + 0] = vp0[3 * v + 0] - mx;
        out[o + 1] = vp0[3 * v + 1] - my;
        out[o + 2] = vp0[3 * v + 2] - mz;
    }
    if (tid == 0) {
        size_t mo = offMV + (size_t)tile * 3;
        out[mo + 0] = mx;
        out[mo + 1] = my;
        out[mo + 2] = mz;
    }
    if (tile == 0) {
        for (int i = tid; i < D * 3; i += BLOCK)
            out[offDIR + i] = dirs[i];
        if (tid < 2) out[offZ + tid] = 0.f;
    }
}

// ---------------- Kernel 2: hot per-direction loop ----------------
__global__ __launch_bounds__(BLOCK, 8) void mcnet_hot(
    const float* __restrict__ verts,   // raw verts (cold path only)
    const float* __restrict__ smooth,
    const float* __restrict__ dirs,
    float* __restrict__ out,
    int NT, int V, int D, int SPLIT,
    size_t offDH, size_t offMV, size_t offLV)
{
    __shared__ __align__(16) float Xs[VMAX];
    __shared__ __align__(16) float Ys[VMAX];
    __shared__ __align__(16) float Zs[VMAX];
    __shared__ float acc[4][NSUB - 1][DPB];     // S,Ax,Ay,Az partials

    const int tid  = threadIdx.x;
    const int lane = tid & 63;
    const int wid  = tid >> 6;
    const int tile = blockIdx.x / SPLIT;
    const int s    = blockIdx.x % SPLIT;

    const float* lvp = out + offLV + (size_t)tile * V * 3;   // written by K1
    const bool fast = (V <= VMAX) && ((V & 7) == 0);

    if (fast) {
        for (int v = tid; v < V; v += BLOCK) {
            float a = lvp[3 * v + 0];
            float b = lvp[3 * v + 1];
            float c = lvp[3 * v + 2];
            Xs[v] = a; Ys[v] = b; Zs[v] = c;
        }
    }
    __syncthreads();

    const int d0      = s * DPB + lane;
    const bool active = (d0 < D);
    const int  d      = active ? d0 : (D - 1);

    const float dx = dirs[d * 3 + 0];
    const float dy = dirs[d * 3 + 1];
    const float dz = dirs[d * 3 + 2];
    const float pv = smooth[tile];          // uniform -> s_load
    const float c1 = pv - 1.f;
    const float Sthresh = (float)V * 1e-10f;

    // mean (uniform s_load; epilogue + cold path)
    const float mx = out[offMV + (size_t)tile * 3 + 0];
    const float my = out[offMV + (size_t)tile * 3 + 1];
    const float mz = out[offMV + (size_t)tile * 3 + 2];

    // force chunk index into SGPR
    const int sub  = __builtin_amdgcn_readfirstlane(wid);
    const int VC   = V >> 2;
    const int vbeg = (sub * VC < V) ? sub * VC : V;
    const int vend = (sub == NSUB - 1) ? V : ((vbeg + VC < V) ? vbeg + VC : V);

    float S, Ax, Ay, Az;

    if (fast) {
        const f32x2 dx2 = {dx, dx}, dy2 = {dy, dy}, dz2 = {dz, dz}, c12 = {c1, c1};
        f32x2 S2 = {0.f, 0.f}, Ax2 = {0.f, 0.f}, Ay2 = {0.f, 0.f}, Az2 = {0.f, 0.f};
        #pragma unroll 4
        for (int v = vbeg; v < vend; v += 2) {
            f32x2 x2 = *(const f32x2*)&Xs[v];   // ds_read_b64, broadcast
            f32x2 y2 = *(const f32x2*)&Ys[v];
            f32x2 z2 = *(const f32x2*)&Zs[v];
            // dot: 3 forced VOP3P ops for 2 vertices
            f32x2 t = apk_fma(x2, dx2, apk_fma(y2, dy2, apk_mul(z2, dz2)));
            float zc0 = fmaxf(t.x, 0.f);
            float zc1 = fmaxf(t.y, 0.f);
            f32x2 zc = {zc0, zc1};
            f32x2 l  = {fast_log2(zc0), fast_log2(zc1)};   // -inf at 0
            f32x2 e  = apk_mul(l, c12);
            f32x2 w  = {fast_exp2(e.x), fast_exp2(e.y)};   // z^(p-1), 0 at z<=0
            S2  = apk_fma(w, zc, S2);
            Ax2 = apk_fma(w, x2, Ax2);
            Ay2 = apk_fma(w, y2, Ay2);
            Az2 = apk_fma(w, z2, Az2);
        }
        S  = S2.x + S2.y;
        Ax = Ax2.x + Ax2.y;
        Ay = Ay2.x + Ay2.y;
        Az = Az2.x + Az2.y;
    } else {
        // generic path: scalar, lv from global (uniform loads)
        S = 0.f; Ax = 0.f; Ay = 0.f; Az = 0.f;
        for (int v = vbeg; v < vend; ++v) {
            float lx = lvp[3 * v + 0];
            float ly = lvp[3 * v + 1];
            float lz = lvp[3 * v + 2];
            float z  = fmaf(lx, dx, fmaf(ly, dy, lz * dz));
            float zc = fmaxf(z, 0.f);
            float w  = fast_exp2(c1 * fast_log2(zc));
            S  = fmaf(w, zc, S);
            Ax = fmaf(w, lx, Ax);
            Ay = fmaf(w, ly, Ay);
            Az = fmaf(w, lz, Az);
        }
    }

    // ---- merge the 4 per-wave partials through LDS ----
    if (sub != 0) {
        acc[0][sub - 1][lane] = S;
        acc[1][sub - 1][lane] = Ax;
        acc[2][sub - 1][lane] = Ay;
        acc[3][sub - 1][lane] = Az;
    }
    __syncthreads();
    if (sub != 0) return;

    #pragma unroll
    for (int k = 0; k < NSUB - 1; ++k) {
        S  += acc[0][k][lane];
        Ax += acc[1][k][lane];
        Ay += acc[2][k][lane];
        Az += acc[3][k][lane];
    }

    if (!active) return;

    size_t po  = ((size_t)tile * D + d) * 3;
    size_t dho = offDH + ((size_t)tile * D + d) * 4;

    if (S >= Sthresh) {
        // S >= V*1e-10 => zmax^p >= 1e-10: no k-rescale, exponents bounded,
        // LB floors negligible, UB clip unreachable.
        float h = fminf(fmaxf(fast_exp2(fast_log2(S) * (1.f / pv)), LBv), UBv);
        float scale = fast_exp2(-c1 * fast_log2(h));   // h^-(p-1)
        out[po + 0] = fmaf(Ax, scale, mx);
        out[po + 1] = fmaf(Ay, scale, my);
        out[po + 2] = fmaf(Az, scale, mz);
        out[dho + 0] = dx;
        out[dho + 1] = dy;
        out[dho + 2] = dz;
        out[dho + 3] = h;                               // k == 1
    } else {
        // ---- literal reference semantics (cold; never taken for bench data) ----
        const float* vp0 = verts + (size_t)tile * V * 3;
        float zmax = 0.f;
        for (int v = 0; v < V; ++v) {
            float z = fmaf(vp0[3 * v] - mx, dx,
                      fmaf(vp0[3 * v + 1] - my, dy, (vp0[3 * v + 2] - mz) * dz));
            zmax = fmaxf(zmax, z);
        }
        float zm_log   = (zmax > 0.f) ? log10f(zmax) : -INFINITY;
        float exponent = zm_log * pv;
        float lk = (exponent < -20.f) ? (-20.f - exponent) / pv : 0.f;
        float kk = powf(10.f, fminf(fmaxf(ceilf(lk), 0.f), UBv));

        float sum = 0.f;
        for (int v = 0; v < V; ++v) {
            float z = fmaf(vp0[3 * v] - mx, dx,
                      fmaf(vp0[3 * v + 1] - my, dy, (vp0[3 * v + 2] - mz) * dz));
            float zms = fmaxf(z, 0.f) * kk;
            float w   = (zms > 0.f) ? fminf(fmaxf(powf(zms, pv), LBv), UBv) : 0.f;
            sum += w;
        }
        float h = fminf(fmaxf(powf(sum, 1.f / pv), LBv), UBv);

        float bx = 0.f, by = 0.f, bz = 0.f;
        for (int v = 0; v < V; ++v) {
            float lx = vp0[3 * v] - mx, ly = vp0[3 * v + 1] - my, lz = vp0[3 * v + 2] - mz;
            float z     = fmaf(lx, dx, fmaf(ly, dy, lz * dz));
            float zms   = fmaxf(z, 0.f) * kk;
            float ratio = zms / h;
            float w = (ratio > 0.f) ? fminf(fmaxf(powf(ratio, c1), LBv), UBv) : LBv;
            bx = fmaf(w, lx, bx);
            by = fmaf(w, ly, by);
            bz = fmaf(w, lz, bz);
        }
        out[po + 0] = bx + mx;
        out[po + 1] = by + my;
        out[po + 2] = bz + mz;
        out[dho + 0] = dx;
        out[dho + 1] = dy;
        out[dho + 2] = dz;
        out[dho + 3] = h / kk;
    }
}

extern "C" void kernel_launch(void* const* d_in, const int* in_sizes, int n_in,
                              void* d_out, int out_size, void* d_ws, size_t ws_size,
                              hipStream_t stream) {
    const float* verts  = (const float*)d_in[0];
    const float* smooth = (const float*)d_in[1];
    const float* dirs   = (const float*)d_in[2];
    float* out = (float*)d_out;

    // verts = NT*V*3, smooth = NT, dirs = D*3
    const int NT = in_sizes[1];
    const int D  = in_sizes[2] / 3;
    const int V  = in_sizes[0] / (3 * NT);
    const int SPLIT = (D + DPB - 1) / DPB;               // 64 dirs per block

    const size_t offDH  = (size_t)NT * D * 3;            // after points
    const size_t offMV  = offDH  + (size_t)NT * D * 4;   // after direction_h
    const size_t offDIR = offMV  + (size_t)NT * 3;       // after mean_v
    const size_t offLV  = offDIR + (size_t)D * 3;        // after directions
    const size_t offZ   = offLV  + (size_t)NT * V * 3;   // after local_vertices

    hipLaunchKernelGGL(mcnet_mean, dim3(NT), dim3(BLOCK), 0, stream,
                       verts, dirs, out, NT, V, D, offMV, offDIR, offLV, offZ);
    hipLaunchKernelGGL(mcnet_hot, dim3(NT * SPLIT), dim3(BLOCK), 0, stream,
                       verts, smooth, dirs, out, NT, V, D, SPLIT,
                       offDH, offMV, offLV);
}

// Round 5
// 93.250 us; speedup vs baseline: 10.8871x; 10.8871x over previous
//
#include <hip/hip_runtime.h>
#include <math.h>

#define BLOCK 256
#define DPB   64      // directions per block-item = one wave's lanes
#define NSUB  4       // vertex sub-chunks, one per wave
#define VMAX  1024    // max verts stageable in LDS fast path
#define PGRID 2048    // persistent blocks (8 per CU on 256 CUs)
#define LBv 1e-20f
#define UBv 1e20f

typedef float f32x4 __attribute__((ext_vector_type(4)));

// Raw HW transcendentals: v_log_f32 / v_exp_f32 (~1 ulp).
// Edge semantics used deliberately: log2(0) = -inf, exp2(-inf) = 0 (c1>0).
#if __has_builtin(__builtin_amdgcn_logf) && __has_builtin(__builtin_amdgcn_exp2f)
__device__ __forceinline__ float fast_log2(float x) { return __builtin_amdgcn_logf(x); }
__device__ __forceinline__ float fast_exp2(float x) { return __builtin_amdgcn_exp2f(x); }
#else
__device__ __forceinline__ float fast_log2(float x) { return log2f(x); }
__device__ __forceinline__ float fast_exp2(float x) { return exp2f(x); }
#endif

// ---------------- Kernel 1: once-per-tile work ----------------
__global__ __launch_bounds__(BLOCK) void mcnet_mean(
    const float* __restrict__ verts, const float* __restrict__ dirs,
    float* __restrict__ out,
    int NT, int V, int D,
    size_t offMV, size_t offDIR, size_t offLV, size_t offZ)
{
    __shared__ float red[12];
    const int tid  = threadIdx.x;
    const int lane = tid & 63;
    const int wid  = tid >> 6;
    const int tile = blockIdx.x;

    const float* vp0 = verts + (size_t)tile * V * 3;

    float sx = 0.f, sy = 0.f, sz = 0.f;
    for (int v = tid; v < V; v += BLOCK) {
        sx += vp0[3 * v + 0]; sy += vp0[3 * v + 1]; sz += vp0[3 * v + 2];
    }
    #pragma unroll
    for (int off = 32; off > 0; off >>= 1) {
        sx += __shfl_xor(sx, off);
        sy += __shfl_xor(sy, off);
        sz += __shfl_xor(sz, off);
    }
    if (lane == 0) { red[wid * 3 + 0] = sx; red[wid * 3 + 1] = sy; red[wid * 3 + 2] = sz; }
    __syncthreads();
    const float inv = 1.0f / (float)V;
    const float mx = (red[0] + red[3] + red[6] + red[9])  * inv;
    const float my = (red[1] + red[4] + red[7] + red[10]) * inv;
    const float mz = (red[2] + red[5] + red[8] + red[11]) * inv;

    for (int v = tid; v < V; v += BLOCK) {
        size_t o = offLV + ((size_t)tile * V + v) * 3;
        out[o + 0] = vp0[3 * v + 0] - mx;
        out[o + 1] = vp0[3 * v + 1] - my;
        out[o + 2] = vp0[3 * v + 2] - mz;
    }
    if (tid == 0) {
        size_t mo = offMV + (size_t)tile * 3;
        out[mo + 0] = mx;
        out[mo + 1] = my;
        out[mo + 2] = mz;
    }
    if (tile == 0) {
        for (int i = tid; i < D * 3; i += BLOCK)
            out[offDIR + i] = dirs[i];
        if (tid < 2) out[offZ + tid] = 0.f;
    }
}

// ---------------- Kernel 2: hot per-direction loop (persistent) ----------------
__global__ __launch_bounds__(BLOCK, 8) void mcnet_hot(
    const float* __restrict__ verts,   // raw verts (cold path only)
    const float* __restrict__ smooth,
    const float* __restrict__ dirs,
    float* __restrict__ out,
    int NT, int V, int D, int SPLIT, int NITEMS,
    size_t offDH, size_t offMV, size_t offLV)
{
    __shared__ __align__(16) float Xs[VMAX];
    __shared__ __align__(16) float Ys[VMAX];
    __shared__ __align__(16) float Zs[VMAX];
    __shared__ float acc[3][NSUB - 1][DPB];     // Ax,Ay,Az partials

    const int tid  = threadIdx.x;
    const int lane = tid & 63;
    const int wid  = tid >> 6;
    const int sub  = __builtin_amdgcn_readfirstlane(wid);  // SGPR chunk index
    // fast path: LDS-staged SoA verts, 4-batched loop (needs V%16==0)
    const bool fast = (V <= VMAX) && ((V & 15) == 0);

    for (int item = blockIdx.x; item < NITEMS; item += gridDim.x) {
        const int tile = item / SPLIT;
        const int s    = item - tile * SPLIT;

        const float* lvp = out + offLV + (size_t)tile * V * 3;   // written by K1

        __syncthreads();   // previous item's LDS readers done before restage
        if (fast) {
            for (int v = tid; v < V; v += BLOCK) {
                float a = lvp[3 * v + 0];
                float b = lvp[3 * v + 1];
                float c = lvp[3 * v + 2];
                Xs[v] = a; Ys[v] = b; Zs[v] = c;
            }
        }
        __syncthreads();

        const int d0      = s * DPB + lane;
        const bool active = (d0 < D);
        const int  d      = active ? d0 : (D - 1);

        const float dx = dirs[d * 3 + 0];
        const float dy = dirs[d * 3 + 1];
        const float dz = dirs[d * 3 + 2];
        const float pv = smooth[tile];          // uniform -> s_load
        const float c1 = pv - 1.f;
        const float Sthresh = (float)V * 1e-10f;

        const int VC   = V >> 2;
        const int vbeg = sub * VC;

        float Ax = 0.f, Ay = 0.f, Az = 0.f;

        if (fast) {
            // batch of 4: 3x ds_read_b128, then 4 independent logs / 4 exps
            // (bursts keep the quarter-rate trans pipe fed), then 3x4 fma.
            for (int v = 0; v < VC; v += 4) {
                f32x4 x4 = *(const f32x4*)&Xs[vbeg + v];
                f32x4 y4 = *(const f32x4*)&Ys[vbeg + v];
                f32x4 z4 = *(const f32x4*)&Zs[vbeg + v];
                float zc0 = fmaxf(fmaf(x4.x, dx, fmaf(y4.x, dy, z4.x * dz)), 0.f);
                float zc1 = fmaxf(fmaf(x4.y, dx, fmaf(y4.y, dy, z4.y * dz)), 0.f);
                float zc2 = fmaxf(fmaf(x4.z, dx, fmaf(y4.z, dy, z4.z * dz)), 0.f);
                float zc3 = fmaxf(fmaf(x4.w, dx, fmaf(y4.w, dy, z4.w * dz)), 0.f);
                float l0 = fast_log2(zc0);       // -inf at 0
                float l1 = fast_log2(zc1);
                float l2 = fast_log2(zc2);
                float l3 = fast_log2(zc3);
                float w0 = fast_exp2(c1 * l0);   // z^(p-1), 0 at z<=0
                float w1 = fast_exp2(c1 * l1);
                float w2 = fast_exp2(c1 * l2);
                float w3 = fast_exp2(c1 * l3);
                Ax = fmaf(w0, x4.x, Ax); Ay = fmaf(w0, y4.x, Ay); Az = fmaf(w0, z4.x, Az);
                Ax = fmaf(w1, x4.y, Ax); Ay = fmaf(w1, y4.y, Ay); Az = fmaf(w1, z4.y, Az);
                Ax = fmaf(w2, x4.z, Ax); Ay = fmaf(w2, y4.z, Ay); Az = fmaf(w2, z4.z, Az);
                Ax = fmaf(w3, x4.w, Ax); Ay = fmaf(w3, y4.w, Ay); Az = fmaf(w3, z4.w, Az);
            }
        } else {
            // generic path: scalar, lv from global (uniform loads)
            const int vend = (sub == NSUB - 1) ? V : vbeg + VC;
            for (int v = vbeg; v < vend; ++v) {
                float lx = lvp[3 * v + 0];
                float ly = lvp[3 * v + 1];
                float lz = lvp[3 * v + 2];
                float zc = fmaxf(fmaf(lx, dx, fmaf(ly, dy, lz * dz)), 0.f);
                float w  = fast_exp2(c1 * fast_log2(zc));
                Ax = fmaf(w, lx, Ax);
                Ay = fmaf(w, ly, Ay);
                Az = fmaf(w, lz, Az);
            }
        }

        // ---- merge the 4 per-wave partials through LDS ----
        if (sub != 0) {
            acc[0][sub - 1][lane] = Ax;
            acc[1][sub - 1][lane] = Ay;
            acc[2][sub - 1][lane] = Az;
        }
        __syncthreads();
        if (sub == 0) {
            #pragma unroll
            for (int k = 0; k < NSUB - 1; ++k) {
                Ax += acc[0][k][lane];
                Ay += acc[1][k][lane];
                Az += acc[2][k][lane];
            }
            // S = sum_v w*z = A . d  (exact algebra: w=0 for z<=0)
            float S = fmaf(Ax, dx, fmaf(Ay, dy, Az * dz));

            if (active) {
                const float mx = out[offMV + (size_t)tile * 3 + 0];
                const float my = out[offMV + (size_t)tile * 3 + 1];
                const float mz = out[offMV + (size_t)tile * 3 + 2];

                size_t po  = ((size_t)tile * D + d) * 3;
                size_t dho = offDH + ((size_t)tile * D + d) * 4;

                if (S >= Sthresh) {
                    // S >= V*1e-10 => zmax^p >= 1e-10: no k-rescale, exponents
                    // bounded, LB floors negligible, UB clip unreachable.
                    float h = fminf(fmaxf(fast_exp2(fast_log2(S) * (1.f / pv)), LBv), UBv);
                    float scale = fast_exp2(-c1 * fast_log2(h));   // h^-(p-1)
                    out[po + 0] = fmaf(Ax, scale, mx);
                    out[po + 1] = fmaf(Ay, scale, my);
                    out[po + 2] = fmaf(Az, scale, mz);
                    out[dho + 0] = dx;
                    out[dho + 1] = dy;
                    out[dho + 2] = dz;
                    out[dho + 3] = h;                               // k == 1
                } else {
                    // ---- literal reference semantics (cold; never taken for bench data) ----
                    const float* vp0 = verts + (size_t)tile * V * 3;
                    float zmax = 0.f;
                    for (int v = 0; v < V; ++v) {
                        float z = fmaf(vp0[3 * v] - mx, dx,
                                  fmaf(vp0[3 * v + 1] - my, dy, (vp0[3 * v + 2] - mz) * dz));
                        zmax = fmaxf(zmax, z);
                    }
                    float zm_log   = (zmax > 0.f) ? log10f(zmax) : -INFINITY;
                    float exponent = zm_log * pv;
                    float lk = (exponent < -20.f) ? (-20.f - exponent) / pv : 0.f;
                    float kk = powf(10.f, fminf(fmaxf(ceilf(lk), 0.f), UBv));

                    float sum = 0.f;
                    for (int v = 0; v < V; ++v) {
                        float z = fmaf(vp0[3 * v] - mx, dx,
                                  fmaf(vp0[3 * v + 1] - my, dy, (vp0[3 * v + 2] - mz) * dz));
                        float zms = fmaxf(z, 0.f) * kk;
                        float w   = (zms > 0.f) ? fminf(fmaxf(powf(zms, pv), LBv), UBv) : 0.f;
                        sum += w;
                    }
                    float h = fminf(fmaxf(powf(sum, 1.f / pv), LBv), UBv);

                    float bx = 0.f, by = 0.f, bz = 0.f;
                    for (int v = 0; v < V; ++v) {
                        float lx = vp0[3 * v] - mx, ly = vp0[3 * v + 1] - my, lz = vp0[3 * v + 2] - mz;
                        float z     = fmaf(lx, dx, fmaf(ly, dy, lz * dz));
                        float zms   = fmaxf(z, 0.f) * kk;
                        float ratio = zms / h;
                        float w = (ratio > 0.f) ? fminf(fmaxf(powf(ratio, c1), LBv), UBv) : LBv;
                        bx = fmaf(w, lx, bx);
                        by = fmaf(w, ly, by);
                        bz = fmaf(w, lz, bz);
                    }
                    out[po + 0] = bx + mx;
                    out[po + 1] = by + my;
                    out[po + 2] = bz + mz;
                    out[dho + 0] = dx;
                    out[dho + 1] = dy;
                    out[dho + 2] = dz;
                    out[dho + 3] = h / kk;
                }
            }
        }
    }
}

extern "C" void kernel_launch(void* const* d_in, const int* in_sizes, int n_in,
                              void* d_out, int out_size, void* d_ws, size_t ws_size,
                              hipStream_t stream) {
    const float* verts  = (const float*)d_in[0];
    const float* smooth = (const float*)d_in[1];
    const float* dirs   = (const float*)d_in[2];
    float* out = (float*)d_out;

    // verts = NT*V*3, smooth = NT, dirs = D*3
    const int NT = in_sizes[1];
    const int D  = in_sizes[2] / 3;
    const int V  = in_sizes[0] / (3 * NT);
    const int SPLIT = (D + DPB - 1) / DPB;               // 64 dirs per item

    const size_t offDH  = (size_t)NT * D * 3;            // after points
    const size_t offMV  = offDH  + (size_t)NT * D * 4;   // after direction_h
    const size_t offDIR = offMV  + (size_t)NT * 3;       // after mean_v
    const size_t offLV  = offDIR + (size_t)D * 3;        // after directions
    const size_t offZ   = offLV  + (size_t)NT * V * 3;   // after local_vertices

    const int NITEMS  = NT * SPLIT;
    const int nblocks = (NITEMS < PGRID) ? NITEMS : PGRID;

    hipLaunchKernelGGL(mcnet_mean, dim3(NT), dim3(BLOCK), 0, stream,
                       verts, dirs, out, NT, V, D, offMV, offDIR, offLV, offZ);
    hipLaunchKernelGGL(mcnet_hot, dim3(nblocks), dim3(BLOCK), 0, stream,
                       verts, smooth, dirs, out, NT, V, D, SPLIT, NITEMS,
                       offDH, offMV, offLV);
}

// Round 6
// 87.495 us; speedup vs baseline: 11.6031x; 1.0658x over previous
//
#include <hip/hip_runtime.h>
#include <math.h>

#define BLOCK 256
#define DPB   64      // directions per block-item = one wave's lanes
#define NSUB  4       // vertex sub-chunks, one per wave
#define LBv 1e-20f
#define UBv 1e20f

// Raw HW transcendentals: v_log_f32 / v_exp_f32 (~1 ulp).
// Edge semantics used deliberately: log2(0) = -inf, exp2(-inf) = 0 (c1>0).
#if __has_builtin(__builtin_amdgcn_logf) && __has_builtin(__builtin_amdgcn_exp2f)
__device__ __forceinline__ float fast_log2(float x) { return __builtin_amdgcn_logf(x); }
__device__ __forceinline__ float fast_exp2(float x) { return __builtin_amdgcn_exp2f(x); }
#else
__device__ __forceinline__ float fast_log2(float x) { return log2f(x); }
__device__ __forceinline__ float fast_exp2(float x) { return exp2f(x); }
#endif

// ---------------- Kernel 1: once-per-tile work ----------------
__global__ __launch_bounds__(BLOCK) void mcnet_mean(
    const float* __restrict__ verts, const float* __restrict__ dirs,
    float* __restrict__ out,
    int NT, int V, int D,
    size_t offMV, size_t offDIR, size_t offLV, size_t offZ)
{
    __shared__ float red[12];
    const int tid  = threadIdx.x;
    const int lane = tid & 63;
    const int wid  = tid >> 6;
    const int tile = blockIdx.x;

    const float* vp0 = verts + (size_t)tile * V * 3;

    float sx = 0.f, sy = 0.f, sz = 0.f;
    for (int v = tid; v < V; v += BLOCK) {
        sx += vp0[3 * v + 0]; sy += vp0[3 * v + 1]; sz += vp0[3 * v + 2];
    }
    #pragma unroll
    for (int off = 32; off > 0; off >>= 1) {
        sx += __shfl_xor(sx, off);
        sy += __shfl_xor(sy, off);
        sz += __shfl_xor(sz, off);
    }
    if (lane == 0) { red[wid * 3 + 0] = sx; red[wid * 3 + 1] = sy; red[wid * 3 + 2] = sz; }
    __syncthreads();
    const float inv = 1.0f / (float)V;
    const float mx = (red[0] + red[3] + red[6] + red[9])  * inv;
    const float my = (red[1] + red[4] + red[7] + red[10]) * inv;
    const float mz = (red[2] + red[5] + red[8] + red[11]) * inv;

    for (int v = tid; v < V; v += BLOCK) {
        size_t o = offLV + ((size_t)tile * V + v) * 3;
        out[o + 0] = vp0[3 * v + 0] - mx;
        out[o + 1] = vp0[3 * v + 1] - my;
        out[o + 2] = vp0[3 * v + 2] - mz;
    }
    if (tid == 0) {
        size_t mo = offMV + (size_t)tile * 3;
        out[mo + 0] = mx;
        out[mo + 1] = my;
        out[mo + 2] = mz;
    }
    if (tile == 0) {
        for (int i = tid; i < D * 3; i += BLOCK)
            out[offDIR + i] = dirs[i];
        if (tid < 2) out[offZ + tid] = 0.f;
    }
}

// ---------------- Kernel 2: hot per-direction loop ----------------
// One item = (tile, 64 directions). 4 waves split the V verts; lv is read
// with wave-uniform indices -> s_load_dwordx4 on the scalar pipe (no LDS
// staging, no stage barriers, zero vector-issue cost for operand fetch).
__global__ __launch_bounds__(BLOCK, 8) void mcnet_hot(
    const float* __restrict__ verts,   // raw verts (cold path only)
    const float* __restrict__ smooth,
    const float* __restrict__ dirs,
    float* __restrict__ out,
    int NT, int V, int D, int SPLIT,
    size_t offDH, size_t offMV, size_t offLV)
{
    __shared__ float acc[3][NSUB - 1][DPB];     // Ax,Ay,Az partials

    const int tid  = threadIdx.x;
    const int lane = tid & 63;
    const int wid  = tid >> 6;
    const int sub  = __builtin_amdgcn_readfirstlane(wid);  // SGPR chunk index
    const int tile = blockIdx.x / SPLIT;
    const int s    = blockIdx.x - tile * SPLIT;

    const float* lvp = out + offLV + (size_t)tile * V * 3;   // written by K1

    const int d0      = s * DPB + lane;
    const bool active = (d0 < D);
    const int  d      = active ? d0 : (D - 1);

    const float dx = dirs[d * 3 + 0];
    const float dy = dirs[d * 3 + 1];
    const float dz = dirs[d * 3 + 2];
    const float pv = smooth[tile];          // uniform -> s_load
    const float c1 = pv - 1.f;
    const float Sthresh = (float)V * 1e-10f;

    const int VC   = V >> 2;                // verts per wave-chunk
    const int vbeg = sub * VC;
    const int vend = (sub == NSUB - 1) ? V : vbeg + VC;

    float Ax = 0.f, Ay = 0.f, Az = 0.f;

#define PROC1(lx, ly, lz) do {                                       \
        float zc = fmaxf(fmaf((lx), dx, fmaf((ly), dy, (lz) * dz)), 0.f); \
        float l  = fast_log2(zc);          /* -inf at 0 */           \
        float w  = fast_exp2(c1 * l);      /* z^(p-1), 0 at z<=0 */  \
        Ax = fmaf(w, (lx), Ax);                                      \
        Ay = fmaf(w, (ly), Ay);                                      \
        Az = fmaf(w, (lz), Az);                                      \
    } while (0)

    if ((V & 15) == 0) {
        // batch of 4 verts: 12 uniform floats -> 3x s_load_dwordx4 (scalar
        // pipe). 4 independent log/exp pairs burst-feed the trans pipe.
        #pragma unroll 2
        for (int v = vbeg; v < vend; v += 4) {
            const float* q = lvp + 3 * v;
            float x0 = q[0],  y0 = q[1],  z0 = q[2];
            float x1 = q[3],  y1 = q[4],  z1 = q[5];
            float x2 = q[6],  y2 = q[7],  z2 = q[8];
            float x3 = q[9],  y3 = q[10], z3 = q[11];
            float zc0 = fmaxf(fmaf(x0, dx, fmaf(y0, dy, z0 * dz)), 0.f);
            float zc1 = fmaxf(fmaf(x1, dx, fmaf(y1, dy, z1 * dz)), 0.f);
            float zc2 = fmaxf(fmaf(x2, dx, fmaf(y2, dy, z2 * dz)), 0.f);
            float zc3 = fmaxf(fmaf(x3, dx, fmaf(y3, dy, z3 * dz)), 0.f);
            float l0 = fast_log2(zc0);
            float l1 = fast_log2(zc1);
            float l2 = fast_log2(zc2);
            float l3 = fast_log2(zc3);
            float w0 = fast_exp2(c1 * l0);
            float w1 = fast_exp2(c1 * l1);
            float w2 = fast_exp2(c1 * l2);
            float w3 = fast_exp2(c1 * l3);
            Ax = fmaf(w0, x0, Ax); Ay = fmaf(w0, y0, Ay); Az = fmaf(w0, z0, Az);
            Ax = fmaf(w1, x1, Ax); Ay = fmaf(w1, y1, Ay); Az = fmaf(w1, z1, Az);
            Ax = fmaf(w2, x2, Ax); Ay = fmaf(w2, y2, Ay); Az = fmaf(w2, z2, Az);
            Ax = fmaf(w3, x3, Ax); Ay = fmaf(w3, y3, Ay); Az = fmaf(w3, z3, Az);
        }
    } else {
        for (int v = vbeg; v < vend; ++v)
            PROC1(lvp[3 * v + 0], lvp[3 * v + 1], lvp[3 * v + 2]);
    }

    // ---- merge the 4 per-wave partials through LDS ----
    if (sub != 0) {
        acc[0][sub - 1][lane] = Ax;
        acc[1][sub - 1][lane] = Ay;
        acc[2][sub - 1][lane] = Az;
    }
    __syncthreads();
    if (sub != 0) return;

    #pragma unroll
    for (int k = 0; k < NSUB - 1; ++k) {
        Ax += acc[0][k][lane];
        Ay += acc[1][k][lane];
        Az += acc[2][k][lane];
    }
    // S = sum_v w*z = A . d  (exact algebra: w=0 for z<=0)
    float S = fmaf(Ax, dx, fmaf(Ay, dy, Az * dz));

    if (!active) return;

    const float mx = out[offMV + (size_t)tile * 3 + 0];
    const float my = out[offMV + (size_t)tile * 3 + 1];
    const float mz = out[offMV + (size_t)tile * 3 + 2];

    size_t po  = ((size_t)tile * D + d) * 3;
    size_t dho = offDH + ((size_t)tile * D + d) * 4;

    if (S >= Sthresh) {
        // S >= V*1e-10 => zmax^p >= 1e-10: no k-rescale, exponents bounded,
        // LB floors negligible, UB clip unreachable.
        float h = fminf(fmaxf(fast_exp2(fast_log2(S) * (1.f / pv)), LBv), UBv);
        float scale = fast_exp2(-c1 * fast_log2(h));   // h^-(p-1)
        out[po + 0] = fmaf(Ax, scale, mx);
        out[po + 1] = fmaf(Ay, scale, my);
        out[po + 2] = fmaf(Az, scale, mz);
        out[dho + 0] = dx;
        out[dho + 1] = dy;
        out[dho + 2] = dz;
        out[dho + 3] = h;                               // k == 1
    } else {
        // ---- literal reference semantics (cold; never taken for bench data) ----
        const float* vp0 = verts + (size_t)tile * V * 3;
        float zmax = 0.f;
        for (int v = 0; v < V; ++v) {
            float z = fmaf(vp0[3 * v] - mx, dx,
                      fmaf(vp0[3 * v + 1] - my, dy, (vp0[3 * v + 2] - mz) * dz));
            zmax = fmaxf(zmax, z);
        }
        float zm_log   = (zmax > 0.f) ? log10f(zmax) : -INFINITY;
        float exponent = zm_log * pv;
        float lk = (exponent < -20.f) ? (-20.f - exponent) / pv : 0.f;
        float kk = powf(10.f, fminf(fmaxf(ceilf(lk), 0.f), UBv));

        float sum = 0.f;
        for (int v = 0; v < V; ++v) {
            float z = fmaf(vp0[3 * v] - mx, dx,
                      fmaf(vp0[3 * v + 1] - my, dy, (vp0[3 * v + 2] - mz) * dz));
            float zms = fmaxf(z, 0.f) * kk;
            float w   = (zms > 0.f) ? fminf(fmaxf(powf(zms, pv), LBv), UBv) : 0.f;
            sum += w;
        }
        float h = fminf(fmaxf(powf(sum, 1.f / pv), LBv), UBv);

        float bx = 0.f, by = 0.f, bz = 0.f;
        for (int v = 0; v < V; ++v) {
            float lx = vp0[3 * v] - mx, ly = vp0[3 * v + 1] - my, lz = vp0[3 * v + 2] - mz;
            float z     = fmaf(lx, dx, fmaf(ly, dy, lz * dz));
            float zms   = fmaxf(z, 0.f) * kk;
            float ratio = zms / h;
            float w = (ratio > 0.f) ? fminf(fmaxf(powf(ratio, c1), LBv), UBv) : LBv;
            bx = fmaf(w, lx, bx);
            by = fmaf(w, ly, by);
            bz = fmaf(w, lz, bz);
        }
        out[po + 0] = bx + mx;
        out[po + 1] = by + my;
        out[po + 2] = bz + mz;
        out[dho + 0] = dx;
        out[dho + 1] = dy;
        out[dho + 2] = dz;
        out[dho + 3] = h / kk;
    }
}

extern "C" void kernel_launch(void* const* d_in, const int* in_sizes, int n_in,
                              void* d_out, int out_size, void* d_ws, size_t ws_size,
                              hipStream_t stream) {
    const float* verts  = (const float*)d_in[0];
    const float* smooth = (const float*)d_in[1];
    const float* dirs   = (const float*)d_in[2];
    float* out = (float*)d_out;

    // verts = NT*V*3, smooth = NT, dirs = D*3
    const int NT = in_sizes[1];
    const int D  = in_sizes[2] / 3;
    const int V  = in_sizes[0] / (3 * NT);
    const int SPLIT = (D + DPB - 1) / DPB;               // 64 dirs per block

    const size_t offDH  = (size_t)NT * D * 3;            // after points
    const size_t offMV  = offDH  + (size_t)NT * D * 4;   // after direction_h
    const size_t offDIR = offMV  + (size_t)NT * 3;       // after mean_v
    const size_t offLV  = offDIR + (size_t)D * 3;        // after directions
    const size_t offZ   = offLV  + (size_t)NT * V * 3;   // after local_vertices

    hipLaunchKernelGGL(mcnet_mean, dim3(NT), dim3(BLOCK), 0, stream,
                       verts, dirs, out, NT, V, D, offMV, offDIR, offLV, offZ);
    hipLaunchKernelGGL(mcnet_hot, dim3(NT * SPLIT), dim3(BLOCK), 0, stream,
                       verts, smooth, dirs, out, NT, V, D, SPLIT,
                       offDH, offMV, offLV);
}